// Round 12
// baseline (754.239 us; speedup 1.0000x reference)
//
#include <hip/hip_runtime.h>
#include <cstddef>

// DifferentiableRollout: x_{t+1} = x + DT * ( tanh([x,u]@W1 + b1) @ W2 + b2 )
// B=1024, T=200, SD=64, CD=32, H=512.  fp32 only.
//
// Confirmed properties (R5-R15 counters):
//  1) Weights MUST stream from L2 via the preload-then-compiler-remat idiom.
//     Explicit residency (LDS or pinned regs) regressed every time
//     (R8/R9 scratch spill 8.5ms; R13/R14 LDS +120-170us).
//  2) pk_fma (packed fp32) halves FMA issue: R12 788->707.
//  3) LDS wave-instr count is first-order: halving broadcasts R15 707->664.
//  Remaining: ~3600 idle cyc/step = barrier drains (vmcnt(0)+lgkmcnt(0) x4)
//  with a SINGLE barrier group per CU -- nothing co-resident to overlap.
//
// R16 (this round): two independent barrier groups per CU.
//  - 512-thread blocks, ROWS_=2 rows each, grid=512 -> 2 blocks/CU
//    (LDS 45KB x2 = 90KB < 160; 8 waves x2 = 16 waves, same occupancy).
//  - While block A drains a barrier, block B issues FMAs: the idle
//    converts to overlap.  Per-CU totals (FMA, LDS instrs, L2 stream)
//    unchanged.
//  - GEMM1: KSLICES=8 (ks=tid>>6 wave-uniform), 4 j-pair-groups/thread
//    (j0+128m), KLEN=12 xcT b64 broadcasts.  96 pk_fma.
//  - GEMM2: wave wv (0..7) owns 64 h; l5 splits 32/32; lane = sf-pair.
//    32 f2 W2 remat loads, 16 b128 pbuf broadcasts, 64 pk_fma.
//    part2[2][16][64], 16-way tree reduce by tid<128.
//  - All LDS access patterns <=2-way bank aliasing (free, m136).
//  Verify: dur 540-600, WG 512, LDS ~46K, VALU 65-75%, FETCH ~15-16MB /
//  WRITE ~59MB / VGPR<=64 (spill tripwire), absmax ~0.25.

constexpr int B_  = 1024;
constexpr int T_  = 200;
constexpr int SD_ = 64;
constexpr int CD_ = 32;
constexpr int H_  = 512;
constexpr int KD_ = SD_ + CD_;   // 96
constexpr float DT_ = 0.1f;
constexpr int ROWS_ = 2;
constexpr int THREADS_ = 512;
constexpr int KSLICES_ = 8;      // GEMM1 K split (wave-uniform: tid>>6)
constexpr int KLEN_ = KD_ / KSLICES_;   // 12
constexpr int JREP_ = 4;         // j-pair groups per thread (stride 128 cols)

typedef float f2 __attribute__((ext_vector_type(2)));

__global__ __launch_bounds__(THREADS_)
void rollout_r16_kernel(
    const float* __restrict__ x0,     // [B, SD]
    const float* __restrict__ ctrl,   // [B, T, CD]
    const float* __restrict__ W1,     // [KD, H]
    const float* __restrict__ b1,     // [H]
    const float* __restrict__ W2,     // [H, SD]
    const float* __restrict__ b2,     // [SD]
    float* __restrict__ out)          // [B, T+1, SD]
{
    __shared__ __align__(16) float xcT[KD_][ROWS_];            // 768 B
    __shared__ __align__(16) float part1[KSLICES_][ROWS_][H_]; // 32 KB
    __shared__ __align__(16) float pbuf[ROWS_][H_];            // 4 KB
    __shared__ __align__(16) float part2[ROWS_][16][SD_];      // 8 KB

    const int tid = threadIdx.x;
    const int r0  = blockIdx.x * ROWS_;

    // ---- GEMM1 mapping: (ks = tid>>6 wave-uniform, jpg = tid&63) ----
    // thread owns 4 j-pairs: columns j0+128m, m=0..3
    const int jpg   = tid & 63;
    const int ks    = tid >> 6;         // 0..7 (wave-uniform)
    const int j0    = jpg * 2;
    const int kbase = ks * KLEN_;
    f2 w1p[JREP_][KLEN_];               // preload -> compiler remats (idiom)
    #pragma unroll
    for (int m = 0; m < JREP_; ++m)
        #pragma unroll
        for (int i = 0; i < KLEN_; ++i)
            w1p[m][i] = *(const f2*)&W1[(size_t)(kbase + i) * H_ + j0 + 128 * m];

    // ---- GEMM2 mapping: wave wv (0..7) owns 64 h; l5 splits; sf-pair ----
    const int wv    = tid >> 6;
    const int lane  = tid & 63;
    const int l5    = lane >> 5;        // 0,1
    const int sfp   = lane & 31;
    const int sf0   = sfp * 2;
    const int hbase = wv * 64 + l5 * 32;
    f2 w2p[32];                         // preload -> remat (idiom)
    #pragma unroll
    for (int i = 0; i < 32; ++i)
        w2p[i] = *(const f2*)&W2[(size_t)(hbase + i) * SD_ + sf0];

    // ---- finish mapping: (rF, jjF pair) ----
    const int rF  = tid >> 8;           // 0..1
    const int jjF = (tid & 255) * 2;
    const f2 bj2 = {b1[jjF], b1[jjF + 1]};

    // reduce/update mapping (tid < 128)
    const int rf = (tid >> 6) & 1;
    const int sf = tid & 63;
    const float bs = b2[sf];

    // ctrl loader: tids [256, 320)
    const int  lt = tid - 256;
    const bool loader = (lt >= 0) && (lt < ROWS_ * CD_);
    const int  lr = (lt >> 5) & 1;
    const int  lc = lt & 31;
    const size_t ctrl_base = (size_t)(r0 + lr) * T_ * CD_ + lc;

    // ---- init: x0 into xcT + states[:,0,:], ctrl[0] into xcT ----
    if (tid < ROWS_ * SD_) {
        const float v = x0[(size_t)(r0 + rf) * SD_ + sf];
        xcT[sf][rf] = v;
        out[(size_t)(r0 + rf) * (T_ + 1) * SD_ + sf] = v;
    }
    if (loader) xcT[SD_ + lc][lr] = ctrl[ctrl_base];
    __syncthreads();

    for (int t = 0; t < T_; ++t) {
        // ---- prefetch next step's controls into a register ----
        float cpre = 0.f;
        if (loader && (t + 1 < T_))
            cpre = ctrl[ctrl_base + (size_t)(t + 1) * CD_];

        // ---- GEMM1 rank-12 partials: 2 rows x 4 j-pairs per thread ----
        f2 acc[ROWS_][JREP_];
        #pragma unroll
        for (int r = 0; r < ROWS_; ++r)
            #pragma unroll
            for (int m = 0; m < JREP_; ++m)
                acc[r][m] = (f2){0.f, 0.f};
        #pragma unroll
        for (int i = 0; i < KLEN_; ++i) {
            const f2 xv = *(const f2*)&xcT[kbase + i][0];  // 1-addr b64 bcast
            #pragma unroll
            for (int m = 0; m < JREP_; ++m) {
                const f2 w = w1p[m][i];
                acc[0][m] = __builtin_elementwise_fma(w, (f2){xv.x, xv.x}, acc[0][m]);
                acc[1][m] = __builtin_elementwise_fma(w, (f2){xv.y, xv.y}, acc[1][m]);
            }
        }
        #pragma unroll
        for (int m = 0; m < JREP_; ++m) {
            *(f2*)&part1[ks][0][j0 + 128 * m] = acc[0][m];
            *(f2*)&part1[ks][1][j0 + 128 * m] = acc[1][m];
        }
        __syncthreads();   // A: part1 visible; all step-t xcT reads done

        // ---- finish: tree-sum 8 slices + bias, tanh x2, all threads ----
        {
            const f2 s0 = *(const f2*)&part1[0][rF][jjF] + *(const f2*)&part1[1][rF][jjF];
            const f2 s1 = *(const f2*)&part1[2][rF][jjF] + *(const f2*)&part1[3][rF][jjF];
            const f2 s2 = *(const f2*)&part1[4][rF][jjF] + *(const f2*)&part1[5][rF][jjF];
            const f2 s3 = *(const f2*)&part1[6][rF][jjF] + *(const f2*)&part1[7][rF][jjF];
            const f2 s  = ((s0 + s1) + (s2 + s3)) + bj2;
            f2 hv;
            hv.x = tanhf(s.x);
            hv.y = tanhf(s.y);
            *(f2*)&pbuf[rF][jjF] = hv;
            if (loader && (t + 1 < T_))
                xcT[SD_ + lc][lr] = cpre;   // step-t xcT reads done at A
        }
        __syncthreads();   // B: activations visible

        // ---- GEMM2: wave wv, lane's 32-h half-chunk, sf-pair wide ----
        {
            f2 q0 = {0.f, 0.f}, q1 = {0.f, 0.f};
            #pragma unroll
            for (int i4 = 0; i4 < 32; i4 += 4) {
                const float4 h0 = *(const float4*)&pbuf[0][hbase + i4]; // 2-addr bcast
                const float4 h1 = *(const float4*)&pbuf[1][hbase + i4];
                q0 = __builtin_elementwise_fma((f2){h0.x, h0.x}, w2p[i4 + 0], q0);
                q0 = __builtin_elementwise_fma((f2){h0.y, h0.y}, w2p[i4 + 1], q0);
                q0 = __builtin_elementwise_fma((f2){h0.z, h0.z}, w2p[i4 + 2], q0);
                q0 = __builtin_elementwise_fma((f2){h0.w, h0.w}, w2p[i4 + 3], q0);
                q1 = __builtin_elementwise_fma((f2){h1.x, h1.x}, w2p[i4 + 0], q1);
                q1 = __builtin_elementwise_fma((f2){h1.y, h1.y}, w2p[i4 + 1], q1);
                q1 = __builtin_elementwise_fma((f2){h1.z, h1.z}, w2p[i4 + 2], q1);
                q1 = __builtin_elementwise_fma((f2){h1.w, h1.w}, w2p[i4 + 3], q1);
            }
            const int c = wv * 2 + l5;          // 0..15
            *(f2*)&part2[0][c][sf0] = q0;       // 2-way bank use: free
            *(f2*)&part2[1][c][sf0] = q1;
        }
        __syncthreads();   // C: part2 visible

        // ---- 16-way tree reduce + state update: tid < 128 ----
        if (tid < ROWS_ * SD_) {
            float v[16];
            #pragma unroll
            for (int c = 0; c < 16; ++c) v[c] = part2[rf][c][sf];
            const float s0 = (v[0] + v[1]) + (v[2] + v[3]);
            const float s1 = (v[4] + v[5]) + (v[6] + v[7]);
            const float s2 = (v[8] + v[9]) + (v[10] + v[11]);
            const float s3 = (v[12] + v[13]) + (v[14] + v[15]);
            const float acc2 = (s0 + s1) + (s2 + s3);
            const float xnew = xcT[sf][rf] + DT_ * (acc2 + bs);
            xcT[sf][rf] = xnew;
            out[(size_t)(r0 + rf) * (T_ + 1) * SD_ + (size_t)(t + 1) * SD_ + sf] = xnew;
        }
        __syncthreads();   // D: new state visible; part2/pbuf reads done
    }
}

extern "C" void kernel_launch(void* const* d_in, const int* in_sizes, int n_in,
                              void* d_out, int out_size, void* d_ws, size_t ws_size,
                              hipStream_t stream) {
    const float* x0   = (const float*)d_in[0];
    const float* ctrl = (const float*)d_in[1];
    const float* W1   = (const float*)d_in[2];
    const float* b1   = (const float*)d_in[3];
    const float* W2   = (const float*)d_in[4];
    const float* b2   = (const float*)d_in[5];
    float* out = (float*)d_out;

    dim3 grid(B_ / ROWS_);      // 512 blocks -> 2 per CU (overlapping groups)
    dim3 block(THREADS_);
    rollout_r16_kernel<<<grid, block, 0, stream>>>(x0, ctrl, W1, b1, W2, b2, out);
}

// Round 13
// 635.221 us; speedup vs baseline: 1.1874x; 1.1874x over previous
//
#include <hip/hip_runtime.h>
#include <cstddef>

// DifferentiableRollout: x_{t+1} = x + DT * ( tanh([x,u]@W1 + b1) @ W2 + b2 )
// B=1024, T=200, SD=64, CD=32, H=512.  fp32 only.
//
// Confirmed properties (R5-R16 counters):
//  1) Weights MUST stream from L2 via preload-then-compiler-remat.  Explicit
//     residency (LDS or pinned regs) regressed every time (R8/R9 spill
//     8.5ms; R13/R14 LDS +120-170us).
//  2) pk_fma halves FMA issue: R12 788->707.
//  3) LDS wave-instr count is first-order: halving broadcasts R15 707->664.
//  4) 512-thread blocks do NOT co-schedule 2/CU (R16: occupancy 46->23%,
//     sequential passes, 754us).  Stay at 1024 threads / 256 blocks.
//  Remaining: ~3600 idle cyc/step ~ 4 barrier drains x ~900 cyc.
//
// R17 (this round): R15 + barrier B eliminated via owner-wave finish fusion.
//  - Wave wv consumes pbuf cols [32wv,32wv+32) in GEMM2 -- so wave wv now
//    also COMPUTES the finish for exactly those 128 values:
//    lane l: row rP=l>>4, col-pair jF=wv*32+(l&15)*2; read part1[k][rP][jF]
//    (f2, k=0..7), tree-sum + bias, tanh x2, write pbuf[rP][jF].
//    finish->GEMM2 is then in-wave LDS store->load (lgkmcnt, NO barrier).
//  - 3 barriers/step: A (part1), C (part2), D (state).
//  - W2 remat loads hoistable into the tanh window (no barrier between).
//  - All arithmetic orders bit-identical to R15; only thread assignment of
//    the finish changed.  GEMM1 / GEMM2 / reduce / weight idiom untouched.
//  Verify: dur 580-620, VALU 60-66%, occupancy ~46%, LDS 108032,
//  FETCH ~15.7MB / WRITE ~59.6MB / VGPR<=64 (spill tripwire), absmax 0.25.

constexpr int B_  = 1024;
constexpr int T_  = 200;
constexpr int SD_ = 64;
constexpr int CD_ = 32;
constexpr int H_  = 512;
constexpr int KD_ = SD_ + CD_;   // 96
constexpr float DT_ = 0.1f;
constexpr int ROWS_ = 4;
constexpr int THREADS_ = 1024;
constexpr int KSLICES_ = 8;      // GEMM1 K split (wave-uniform: tid>>7)
constexpr int KLEN_ = KD_ / KSLICES_;   // 12

typedef float f2 __attribute__((ext_vector_type(2)));

__global__ __launch_bounds__(THREADS_)
void rollout_r17_kernel(
    const float* __restrict__ x0,     // [B, SD]
    const float* __restrict__ ctrl,   // [B, T, CD]
    const float* __restrict__ W1,     // [KD, H]
    const float* __restrict__ b1,     // [H]
    const float* __restrict__ W2,     // [H, SD]
    const float* __restrict__ b2,     // [SD]
    float* __restrict__ out)          // [B, T+1, SD]
{
    __shared__ __align__(16) float xcT[KD_][ROWS_];            // 1.5 KB
    __shared__ __align__(16) float part1[KSLICES_][ROWS_][H_]; // 64 KB
    __shared__ __align__(16) float pbuf[ROWS_][H_];            // 8 KB
    __shared__ __align__(16) float part2[ROWS_][32][SD_];      // 32 KB

    const int tid = threadIdx.x;
    const int r0  = blockIdx.x * ROWS_;

    // ---- GEMM1 mapping: (ks = tid>>7 wave-uniform, jpg = tid&127) ----
    // thread owns j-pairs {2*jpg, 2*jpg+1} and {2*jpg+256, 2*jpg+257}
    const int jpg   = tid & 127;
    const int ks    = tid >> 7;         // 0..7 (wave-uniform: 2 waves/slice)
    const int j0    = jpg * 2;
    const int kbase = ks * KLEN_;
    f2 w1a[KLEN_], w1b[KLEN_];          // preload -> compiler remats (idiom)
    #pragma unroll
    for (int i = 0; i < KLEN_; ++i) {
        w1a[i] = *(const f2*)&W1[(size_t)(kbase + i) * H_ + j0];
        w1b[i] = *(const f2*)&W1[(size_t)(kbase + i) * H_ + j0 + 256];
    }

    // ---- GEMM2 mapping: wave wv, lane = (l5, sfp) ----
    const int wv    = tid >> 6;         // 0..15
    const int lane  = tid & 63;
    const int l5    = lane >> 5;        // 0,1
    const int sfp   = lane & 31;
    const int sf0   = sfp * 2;
    const int hbase = wv * 32 + l5 * 16;
    f2 w2p[16];                         // preload -> remat (idiom)
    #pragma unroll
    for (int i = 0; i < 16; ++i)
        w2p[i] = *(const f2*)&W2[(size_t)(hbase + i) * SD_ + sf0];

    // ---- fused-finish mapping (owner wave wv): lane -> (rP, jF pair) ----
    const int rP = lane >> 4;                  // 0..3
    const int jF = wv * 32 + (lane & 15) * 2;  // within own 32-col chunk
    const f2 bjF = {b1[jF], b1[jF + 1]};

    // reduce/update mapping (tid < 256)
    const int rf = (tid >> 6) & 3;
    const int sf = tid & 63;
    const float bs = b2[sf];

    // ctrl loader: tids [512, 640)
    const int  lt = tid - 512;
    const bool loader = (lt >= 0) && (lt < ROWS_ * CD_);
    const int  lr = (lt >> 5) & 3;
    const int  lc = lt & 31;
    const size_t ctrl_base = (size_t)(r0 + lr) * T_ * CD_ + lc;

    // ---- init: x0 into xcT + states[:,0,:], ctrl[0] into xcT ----
    if (tid < ROWS_ * SD_) {
        const float v = x0[(size_t)(r0 + rf) * SD_ + sf];
        xcT[sf][rf] = v;
        out[(size_t)(r0 + rf) * (T_ + 1) * SD_ + sf] = v;
    }
    if (loader) xcT[SD_ + lc][lr] = ctrl[ctrl_base];
    __syncthreads();

    for (int t = 0; t < T_; ++t) {
        // ---- prefetch next step's controls into a register ----
        float cpre = 0.f;
        if (loader && (t + 1 < T_))
            cpre = ctrl[ctrl_base + (size_t)(t + 1) * CD_];

        // ---- GEMM1 rank-12 partials: 4 rows x TWO j-pairs per thread ----
        f2 a0 = {0.f,0.f}, a1 = {0.f,0.f}, a2 = {0.f,0.f}, a3 = {0.f,0.f};
        f2 b0 = {0.f,0.f}, b1v = {0.f,0.f}, b2v = {0.f,0.f}, b3 = {0.f,0.f};
        #pragma unroll
        for (int i = 0; i < KLEN_; ++i) {
            const float4 xv = *(const float4*)&xcT[kbase + i][0];  // 1-addr bcast
            const f2 wa = w1a[i];
            const f2 wb = w1b[i];
            a0  = __builtin_elementwise_fma(wa, (f2){xv.x, xv.x}, a0);
            a1  = __builtin_elementwise_fma(wa, (f2){xv.y, xv.y}, a1);
            a2  = __builtin_elementwise_fma(wa, (f2){xv.z, xv.z}, a2);
            a3  = __builtin_elementwise_fma(wa, (f2){xv.w, xv.w}, a3);
            b0  = __builtin_elementwise_fma(wb, (f2){xv.x, xv.x}, b0);
            b1v = __builtin_elementwise_fma(wb, (f2){xv.y, xv.y}, b1v);
            b2v = __builtin_elementwise_fma(wb, (f2){xv.z, xv.z}, b2v);
            b3  = __builtin_elementwise_fma(wb, (f2){xv.w, xv.w}, b3);
        }
        *(f2*)&part1[ks][0][j0] = a0;
        *(f2*)&part1[ks][1][j0] = a1;
        *(f2*)&part1[ks][2][j0] = a2;
        *(f2*)&part1[ks][3][j0] = a3;
        *(f2*)&part1[ks][0][j0 + 256] = b0;
        *(f2*)&part1[ks][1][j0 + 256] = b1v;
        *(f2*)&part1[ks][2][j0 + 256] = b2v;
        *(f2*)&part1[ks][3][j0 + 256] = b3;
        __syncthreads();   // A: part1 visible; all step-t xcT reads done

        // ---- fused finish (owner wave) + GEMM2, no barrier between ----
        {
            // finish: tree-sum 8 slices + bias, tanh x2 (own 32-col chunk)
            const f2 s0 = *(const f2*)&part1[0][rP][jF] + *(const f2*)&part1[1][rP][jF];
            const f2 s1 = *(const f2*)&part1[2][rP][jF] + *(const f2*)&part1[3][rP][jF];
            const f2 s2 = *(const f2*)&part1[4][rP][jF] + *(const f2*)&part1[5][rP][jF];
            const f2 s3 = *(const f2*)&part1[6][rP][jF] + *(const f2*)&part1[7][rP][jF];
            const f2 s  = ((s0 + s1) + (s2 + s3)) + bjF;
            f2 hv;
            hv.x = tanhf(s.x);
            hv.y = tanhf(s.y);
            *(f2*)&pbuf[rP][jF] = hv;          // in-wave store...
            if (loader && (t + 1 < T_))
                xcT[SD_ + lc][lr] = cpre;      // step-t xcT reads done at A
        }
        // ...in-wave load (compiler orders via lgkmcnt; reads only own chunk)
        {
            f2 q0 = {0.f,0.f}, q1 = {0.f,0.f}, q2 = {0.f,0.f}, q3 = {0.f,0.f};
            #pragma unroll
            for (int i4 = 0; i4 < 16; i4 += 4) {
                const float4 h0 = *(const float4*)&pbuf[0][hbase + i4]; // 2-addr bcast
                const float4 h1 = *(const float4*)&pbuf[1][hbase + i4];
                const float4 h2 = *(const float4*)&pbuf[2][hbase + i4];
                const float4 h3 = *(const float4*)&pbuf[3][hbase + i4];
                q0 = __builtin_elementwise_fma((f2){h0.x, h0.x}, w2p[i4 + 0], q0);
                q0 = __builtin_elementwise_fma((f2){h0.y, h0.y}, w2p[i4 + 1], q0);
                q0 = __builtin_elementwise_fma((f2){h0.z, h0.z}, w2p[i4 + 2], q0);
                q0 = __builtin_elementwise_fma((f2){h0.w, h0.w}, w2p[i4 + 3], q0);
                q1 = __builtin_elementwise_fma((f2){h1.x, h1.x}, w2p[i4 + 0], q1);
                q1 = __builtin_elementwise_fma((f2){h1.y, h1.y}, w2p[i4 + 1], q1);
                q1 = __builtin_elementwise_fma((f2){h1.z, h1.z}, w2p[i4 + 2], q1);
                q1 = __builtin_elementwise_fma((f2){h1.w, h1.w}, w2p[i4 + 3], q1);
                q2 = __builtin_elementwise_fma((f2){h2.x, h2.x}, w2p[i4 + 0], q2);
                q2 = __builtin_elementwise_fma((f2){h2.y, h2.y}, w2p[i4 + 1], q2);
                q2 = __builtin_elementwise_fma((f2){h2.z, h2.z}, w2p[i4 + 2], q2);
                q2 = __builtin_elementwise_fma((f2){h2.w, h2.w}, w2p[i4 + 3], q2);
                q3 = __builtin_elementwise_fma((f2){h3.x, h3.x}, w2p[i4 + 0], q3);
                q3 = __builtin_elementwise_fma((f2){h3.y, h3.y}, w2p[i4 + 1], q3);
                q3 = __builtin_elementwise_fma((f2){h3.z, h3.z}, w2p[i4 + 2], q3);
                q3 = __builtin_elementwise_fma((f2){h3.w, h3.w}, w2p[i4 + 3], q3);
            }
            const int c = wv * 2 + l5;          // 0..31
            *(f2*)&part2[0][c][sf0] = q0;       // 2-way bank use: free
            *(f2*)&part2[1][c][sf0] = q1;
            *(f2*)&part2[2][c][sf0] = q2;
            *(f2*)&part2[3][c][sf0] = q3;
        }
        __syncthreads();   // C: part2 visible

        // ---- 32-way tree reduce + state update: tid < 256 ----
        if (tid < ROWS_ * SD_) {
            float v[32];
            #pragma unroll
            for (int c = 0; c < 32; ++c) v[c] = part2[rf][c][sf];
            float s[8];
            #pragma unroll
            for (int c = 0; c < 8; ++c)
                s[c] = (v[4*c] + v[4*c+1]) + (v[4*c+2] + v[4*c+3]);
            const float acc = ((s[0] + s[1]) + (s[2] + s[3]))
                            + ((s[4] + s[5]) + (s[6] + s[7]));
            const float xnew = xcT[sf][rf] + DT_ * (acc + bs);
            xcT[sf][rf] = xnew;
            out[(size_t)(r0 + rf) * (T_ + 1) * SD_ + (size_t)(t + 1) * SD_ + sf] = xnew;
        }
        __syncthreads();   // D: new state visible; part2/pbuf reads done
    }
}

extern "C" void kernel_launch(void* const* d_in, const int* in_sizes, int n_in,
                              void* d_out, int out_size, void* d_ws, size_t ws_size,
                              hipStream_t stream) {
    const float* x0   = (const float*)d_in[0];
    const float* ctrl = (const float*)d_in[1];
    const float* W1   = (const float*)d_in[2];
    const float* b1   = (const float*)d_in[3];
    const float* W2   = (const float*)d_in[4];
    const float* b2   = (const float*)d_in[5];
    float* out = (float*)d_out;

    dim3 grid(B_ / ROWS_);      // 256 blocks -> 1 per CU (persistent)
    dim3 block(THREADS_);
    rollout_r17_kernel<<<grid, block, 0, stream>>>(x0, ctrl, W1, b1, W2, b2, out);
}